// Round 3
// baseline (432.540 us; speedup 1.0000x reference)
//
#include <hip/hip_runtime.h>

#define BB 262144
#define TT 20
#define HH 10

static constexpr float L2E = 1.44269504088896340736f;

typedef float v2f __attribute__((ext_vector_type(2)));

__device__ __forceinline__ float frcp(float x)  { return __builtin_amdgcn_rcpf(x); }
__device__ __forceinline__ float fexp2(float x) { return __builtin_amdgcn_exp2f(x); }
__device__ __forceinline__ v2f vfma2(v2f a, v2f b, v2f c) { return __builtin_elementwise_fma(a, b, c); }

// h held in named v2f regs ha..he = (h0,h1),(h2,h3),...,(h8,h9)
#define DOT5(ACC, PTR, BASE) \
    ACC = vfma2(ha, (PTR)[(BASE)+0], ACC); \
    ACC = vfma2(hb, (PTR)[(BASE)+1], ACC); \
    ACC = vfma2(hc, (PTR)[(BASE)+2], ACC); \
    ACC = vfma2(hd, (PTR)[(BASE)+3], ACC); \
    ACC = vfma2(he, (PTR)[(BASE)+4], ACC);

// one LSTM unit: gates -> c update (single rcp) -> h update
#define UNIT(J, CR, HNR) { \
    v2f ai = {0.f,0.f}, af = {0.f,0.f}, ag = {0.f,0.f}, ao = {0.f,0.f}; \
    DOT5(ai, Wh2, (0*HH+(J))*5) \
    DOT5(af, Wh2, (1*HH+(J))*5) \
    DOT5(ag, Wh2, (2*HH+(J))*5) \
    DOT5(ao, Wh2, (3*HH+(J))*5) \
    float gi = ai.x + ai.y + fmaf(x, W_ih[0*HH+(J)], bbf[0*HH+(J)]); \
    float gf = af.x + af.y + fmaf(x, W_ih[1*HH+(J)], bbf[1*HH+(J)]); \
    float gg = ag.x + ag.y + fmaf(x, W_ih[2*HH+(J)], bbf[2*HH+(J)]); \
    float go = ao.x + ao.y + fmaf(x, W_ih[3*HH+(J)], bbf[3*HH+(J)]); \
    float ef = fexp2(gf * (-L2E)); \
    float ei = fexp2(gi * (-L2E)); \
    float eg = fexp2(gg * (2.0f*L2E)); \
    float t1 = 1.0f + ef, t2 = 1.0f + ei; \
    float t3 = eg + 1.0f, t4 = eg - 1.0f; \
    float t5 = t2 * t3; \
    float cn = fmaf((CR), t5, t4 * t1) * frcp(t1 * t5); \
    (CR) = cn; \
    float eo = fexp2(go * (-L2E)); \
    float ec = fexp2(cn * (2.0f*L2E)); \
    (HNR) = (ec - 1.0f) * frcp((1.0f + eo) * (ec + 1.0f)); \
}

#define SCOREM(M) { \
    v2f a2 = {0.f,0.f}; \
    DOT5(a2, W1v, (M)*5) \
    float a = a2.x + a2.y + b1[M]; \
    a = fmaxf(a, 0.2f * a); \
    z = fmaf(a, W2[M], z); \
}

// one time step: score on pre-update h, then LSTM update
#define STEP(X, SREF) { \
    const float x = (X); \
    float z = b2[0]; \
    SCOREM(0) SCOREM(1) SCOREM(2) SCOREM(3) SCOREM(4) \
    (SREF) = frcp(1.0f + fexp2(z * (-L2E))); \
    v2f na, nb, nc, nd, ne; \
    UNIT(0, cva.x, na.x) UNIT(1, cva.y, na.y) \
    UNIT(2, cvb.x, nb.x) UNIT(3, cvb.y, nb.y) \
    UNIT(4, cvc.x, nc.x) UNIT(5, cvc.y, nc.y) \
    UNIT(6, cvd.x, nd.x) UNIT(7, cvd.y, nd.y) \
    UNIT(8, cve.x, ne.x) UNIT(9, cve.y, ne.y) \
    ha = na; hb = nb; hc = nc; hd = nd; he = ne; \
}

__global__ __launch_bounds__(256, 2) void lstm_disc_kernel(
    const float* __restrict__ values, const float* __restrict__ masks,
    const float* __restrict__ W_ih, const float* __restrict__ W_hh,
    const float* __restrict__ b_ih, const float* __restrict__ b_hh,
    const float* __restrict__ W1, const float* __restrict__ b1,
    const float* __restrict__ W2, const float* __restrict__ b2,
    const int* __restrict__ directp,
    float* __restrict__ out)
{
    const int b = blockIdx.x * blockDim.x + threadIdx.x;
    if (b >= BB) return;
    const int dir = *directp;

    // ---- masks pass-through first: loads issue early, overlap with compute ----
    {
        const float* mrow = masks + (size_t)b * TT;
        float* mout = out + (size_t)BB * TT + (size_t)b * TT;
        if (dir == 0) {
            const float4* m4 = (const float4*)mrow;
            float4* o4 = (float4*)mout;
            #pragma unroll
            for (int i = 0; i < TT / 4; ++i) o4[i] = m4[i];
        } else {
            #pragma unroll
            for (int t = 0; t < TT; ++t) mout[t] = mrow[TT - 1 - t];
        }
    }

    const v2f* __restrict__ Wh2 = (const v2f*)W_hh;   // 200 pairs
    const v2f* __restrict__ W1v = (const v2f*)W1;     // 25 pairs

    // combined biases, plain-float array (constant indices only)
    float bbf[4 * HH];
    #pragma unroll
    for (int i = 0; i < 4 * HH; ++i) bbf[i] = b_ih[i] + b_hh[i];

    v2f ha = {0.f,0.f}, hb = {0.f,0.f}, hc = {0.f,0.f}, hd = {0.f,0.f}, he = {0.f,0.f};
    v2f cva = {0.f,0.f}, cvb = {0.f,0.f}, cvc = {0.f,0.f}, cvd = {0.f,0.f}, cve = {0.f,0.f};

    const float2* __restrict__ vp2 = (const float2*)(values + (size_t)b * TT);
    float2* __restrict__ sp2 = (float2*)(out + (size_t)b * TT);

    // rolled time loop: 10 iters x 2 steps; prefetch next value pair
    float2 p = vp2[dir ? 9 : 0];
    #pragma unroll 1
    for (int tb = 0; tb < 10; ++tb) {
        const int nxt = (tb < 9) ? (tb + 1) : 9;
        const float2 pn = vp2[dir ? (9 - nxt) : nxt];

        const float x0 = dir ? p.y : p.x;
        const float x1 = dir ? p.x : p.y;

        float s0, s1;
        STEP(x0, s0)
        STEP(x1, s1)

        float2 sv; sv.x = s0; sv.y = s1;
        sp2[tb] = sv;
        p = pn;
    }
}

extern "C" void kernel_launch(void* const* d_in, const int* in_sizes, int n_in,
                              void* d_out, int out_size, void* d_ws, size_t ws_size,
                              hipStream_t stream) {
    const float* values = (const float*)d_in[0];
    const float* masks  = (const float*)d_in[1];
    const float* W_ih   = (const float*)d_in[2];
    const float* W_hh   = (const float*)d_in[3];
    const float* b_ih   = (const float*)d_in[4];
    const float* b_hh   = (const float*)d_in[5];
    const float* W1     = (const float*)d_in[6];
    const float* b1     = (const float*)d_in[7];
    const float* W2     = (const float*)d_in[8];
    const float* b2     = (const float*)d_in[9];
    const int*   direct = (const int*)d_in[11];
    float* out = (float*)d_out;

    const int block = 256;
    const int grid = (BB + block - 1) / block;
    lstm_disc_kernel<<<grid, block, 0, stream>>>(values, masks, W_ih, W_hh, b_ih, b_hh,
                                                 W1, b1, W2, b2, direct, out);
}